// Round 1
// baseline (1156.534 us; speedup 1.0000x reference)
//
#include <hip/hip_runtime.h>

typedef _Float16 f16;
typedef _Float16 f16x8 __attribute__((ext_vector_type(8)));
typedef _Float16 f16x4 __attribute__((ext_vector_type(4)));
typedef float    f32x4 __attribute__((ext_vector_type(4)));

#define MFMA16(a,b,c) __builtin_amdgcn_mfma_f32_16x16x32_f16(a,b,c,0,0,0)

#define NPIX 65536
#define CSTR 448              // halves per pixel: 7 cb * (32 hi + 32 lo)
#define RB   (256*CSTR*2)     // bytes per buffer row = 229376
#define SBUF ((size_t)258*256*CSTR*2)   // 59,179,008 bytes (258 rows incl. 2 pad)

// weight pack strides (halves)
#define PK_OB   1024
#define PK_CB   14336   // 14*2*512
#define PK_TAP  100352  // 7*PK_CB
#define PK_CONV 903168  // 9*PK_TAP
#define PKL_CB  5120    // 5*2*512
#define PKL_BI  35840   // 7*PKL_CB

// ---------------- weight packing ----------------
__global__ void k_pack_conv(const float* __restrict__ head_w,
                            const float* __restrict__ conv_w,
                            f16* __restrict__ dst)
{
    int t = blockIdx.x*256 + threadIdx.x;
    if (t >= 4*9*7*14*2*64) return;
    int lane = t & 63; t >>= 6;
    int sel  = t & 1;  t >>= 1;
    int ob   = t % 14; t /= 14;
    int cb   = t % 7;  t /= 7;
    int tap  = t % 9;  t /= 9;
    int li   = t;
    const float* W = (li == 0) ? head_w : (conv_w + (size_t)(li-1)*196*196*9);
    int oc  = ob*16 + (lane & 15);
    int ic0 = cb*32 + (lane >> 4)*8;
    f16x8 v;
#pragma unroll
    for (int j = 0; j < 8; ++j) {
        int ic = ic0 + j;
        float x = 0.f;
        if (oc < 196 && ic < 196) x = W[((size_t)oc*196 + ic)*9 + tap];
        f16 h = (f16)x;
        v[j] = (sel == 0) ? h : (f16)(x - (float)h);
    }
    *(f16x8*)(dst + (size_t)li*PK_CONV +
              (((size_t)((tap*7+cb)*14 + ob)*2 + sel)*64 + lane)*8) = v;
}

__global__ void k_pack_last(const float* __restrict__ last_w, f16* __restrict__ dst)
{
    int t = blockIdx.x*256 + threadIdx.x;
    if (t >= 4*7*5*2*64) return;
    int lane = t & 63; t >>= 6;
    int sel  = t & 1;  t >>= 1;
    int ob   = t % 5;  t /= 5;
    int cb   = t % 7;  t /= 7;
    int bi   = t;
    int oc = ob*16 + (lane & 15);
    int k0 = cb*32 + (lane >> 4)*8;
    f16x8 v;
#pragma unroll
    for (int j = 0; j < 8; ++j) {
        int k = k0 + j;
        float x = 0.f;
        if (oc < 68 && k < 196) x = last_w[(size_t)oc*784 + bi*196 + k];
        f16 h = (f16)x;
        v[j] = (sel == 0) ? h : (f16)(x - (float)h);
    }
    *(f16x8*)(dst + (((size_t)((bi*7+cb)*5 + ob)*2 + sel)*64 + lane)*8) = v;
}

// ---------------- warp + concat → x0 ----------------
struct Gath { int o00,o01,o10,o11; float w00,w01,w10,w11; };

__device__ inline Gath mk_gath(float pxf, float pyf)
{
    float x0 = floorf(pxf), y0 = floorf(pyf);
    float x1 = x0 + 1.f, y1 = y0 + 1.f;
    float wx1 = pxf - x0, wx0 = 1.f - wx1;
    float wy1 = pyf - y0, wy0 = 1.f - wy1;
    bool vx0 = (x0 >= 0.f) && (x0 <= 255.f);
    bool vx1 = (x1 >= 0.f) && (x1 <= 255.f);
    bool vy0 = (y0 >= 0.f) && (y0 <= 255.f);
    bool vy1 = (y1 >= 0.f) && (y1 <= 255.f);
    int ix0 = min(max((int)x0, 0), 255);
    int ix1 = min(max((int)x1, 0), 255);
    int iy0 = min(max((int)y0, 0), 255);
    int iy1 = min(max((int)y1, 0), 255);
    Gath g;
    g.o00 = iy0*256 + ix0; g.w00 = (vx0 && vy0) ? wx0*wy0 : 0.f;
    g.o01 = iy0*256 + ix1; g.w01 = (vx1 && vy0) ? wx1*wy0 : 0.f;
    g.o10 = iy1*256 + ix0; g.w10 = (vx0 && vy1) ? wx0*wy1 : 0.f;
    g.o11 = iy1*256 + ix1; g.w11 = (vx1 && vy1) ? wx1*wy1 : 0.f;
    return g;
}

__device__ inline void store4(f16* __restrict__ op, int c0,
                              float a, float b, float c, float d)
{
    f16x4 hi, lo;
    f16 h;
    h = (f16)a; hi[0] = h; lo[0] = (f16)(a - (float)h);
    h = (f16)b; hi[1] = h; lo[1] = (f16)(b - (float)h);
    h = (f16)c; hi[2] = h; lo[2] = (f16)(c - (float)h);
    h = (f16)d; hi[3] = h; lo[3] = (f16)(d - (float)h);
    f16* p = op + (c0 >> 5)*64 + (c0 & 31);
    *(f16x4*)p        = hi;
    *(f16x4*)(p + 32) = lo;
}

__global__ void k_warp_concat(const float* __restrict__ f0, const float* __restrict__ f1,
                              const float* __restrict__ fd, const float* __restrict__ flow,
                              f16* __restrict__ out)
{
    int px = blockIdx.x*256 + threadIdx.x;
    int row = px >> 8, col = px & 255;
    f16* op = out + ((size_t)(row+1)*256 + col)*CSTR;
    Gath g0 = mk_gath((float)col + flow[px],          (float)row + flow[NPIX   + px]);
    Gath g1 = mk_gath((float)col + flow[2*NPIX + px], (float)row + flow[3*NPIX + px]);
#pragma unroll
    for (int c = 0; c < 64; c += 4) {
        float v[4];
#pragma unroll
        for (int r = 0; r < 4; ++r) {
            const float* im = f0 + (size_t)(c+r)*NPIX;
            v[r] = g0.w00*im[g0.o00] + g0.w01*im[g0.o01] + g0.w10*im[g0.o10] + g0.w11*im[g0.o11];
        }
        store4(op, c, v[0], v[1], v[2], v[3]);
    }
#pragma unroll
    for (int c = 0; c < 64; c += 4) {
        float v[4];
#pragma unroll
        for (int r = 0; r < 4; ++r) {
            const float* im = f1 + (size_t)(c+r)*NPIX;
            v[r] = g1.w00*im[g1.o00] + g1.w01*im[g1.o01] + g1.w10*im[g1.o10] + g1.w11*im[g1.o11];
        }
        store4(op, 64 + c, v[0], v[1], v[2], v[3]);
    }
#pragma unroll
    for (int c = 0; c < 64; c += 4) {
        store4(op, 128 + c, fd[(size_t)(c+0)*NPIX + px], fd[(size_t)(c+1)*NPIX + px],
                            fd[(size_t)(c+2)*NPIX + px], fd[(size_t)(c+3)*NPIX + px]);
    }
    store4(op, 192, flow[px], flow[NPIX+px], flow[2*NPIX+px], flow[3*NPIX+px]);
#pragma unroll
    for (int c = 196; c < 224; c += 4) store4(op, c, 0.f, 0.f, 0.f, 0.f);
}

// ---------------- 3x3 conv (196->196, split-f16, fused prelu*mask) ----------------
__global__ __launch_bounds__(256, 2)
void k_conv3x3(const f16* __restrict__ in, f16* __restrict__ out,
               const f16* __restrict__ pack, const float* __restrict__ alpha,
               const float* __restrict__ mask)
{
    int lane = threadIdx.x & 63;
    int wid  = (blockIdx.x << 2) | (threadIdx.x >> 6);
    int ochalf = wid & 1;
    int tile = wid >> 1;
    int row  = tile >> 2;
    int col0 = (tile & 3) << 6;
    int l15 = lane & 15, lk = lane >> 4;

    f32x4 acc[7][4];
#pragma unroll
    for (int i = 0; i < 7; ++i)
#pragma unroll
        for (int j = 0; j < 4; ++j)
            acc[i][j] = (f32x4){0.f, 0.f, 0.f, 0.f};

    const f16x8 Z8 = {(f16)0,(f16)0,(f16)0,(f16)0,(f16)0,(f16)0,(f16)0,(f16)0};
    bool edgeL = (col0 == 0)   && (l15 == 0);
    bool edgeR = (col0 == 192) && (l15 == 15);
    const f16* packw = pack + (size_t)(ochalf*7)*PK_OB + (size_t)lane*8;

    for (int ky = 0; ky < 3; ++ky) {
        for (int kx = 0; kx < 3; ++kx) {
            const f16* bb = in + ((long)((row+ky)*256 + col0 + (kx-1) + l15))*CSTR + lk*8;
            const f16* ap = packw + (size_t)(ky*3 + kx)*PK_TAP;
            bool killL = edgeL && (kx == 0);
            bool killR = edgeR && (kx == 2);
            for (int cb = 0; cb < 7; ++cb) {
                f16x8 bh[4], bl[4];
#pragma unroll
                for (int pb = 0; pb < 4; ++pb) {
                    const f16* p = bb + (size_t)pb*(16*CSTR) + cb*64;
                    bh[pb] = *(const f16x8*)p;
                    bl[pb] = *(const f16x8*)(p + 32);
                }
                if (killL) { bh[0] = Z8; bl[0] = Z8; }
                if (killR) { bh[3] = Z8; bl[3] = Z8; }
                const f16* a = ap + cb*PK_CB;
#pragma unroll
                for (int ob = 0; ob < 7; ++ob) {
                    f16x8 ah = *(const f16x8*)(a + ob*PK_OB);
                    f16x8 al = *(const f16x8*)(a + ob*PK_OB + 512);
#pragma unroll
                    for (int pb = 0; pb < 4; ++pb) {
                        acc[ob][pb] = MFMA16(ah, bh[pb], acc[ob][pb]);
                        acc[ob][pb] = MFMA16(ah, bl[pb], acc[ob][pb]);
                        acc[ob][pb] = MFMA16(al, bh[pb], acc[ob][pb]);
                    }
                }
            }
        }
    }

    float mv[4];
#pragma unroll
    for (int pb = 0; pb < 4; ++pb) mv[pb] = mask[row*256 + col0 + pb*16 + l15];
#pragma unroll
    for (int ob = 0; ob < 7; ++ob) {
        int oc0 = ochalf*112 + ob*16 + lk*4;
        f32x4 a4 = *(const f32x4*)(alpha + min(oc0, 192));
#pragma unroll
        for (int pb = 0; pb < 4; ++pb) {
            f32x4 d = acc[ob][pb];
            f16x4 hi, lo;
#pragma unroll
            for (int r = 0; r < 4; ++r) {
                float v = d[r];
                v = (v >= 0.f ? v : a4[r]*v) * mv[pb];
                f16 h = (f16)v;
                hi[r] = h;
                lo[r] = (f16)(v - (float)h);
            }
            f16* o = out + ((size_t)(row+1)*256 + col0 + pb*16 + l15)*CSTR + (oc0 >> 5)*64 + (oc0 & 31);
            *(f16x4*)o        = hi;
            *(f16x4*)(o + 32) = lo;
        }
    }
}

// ---------------- incremental 1x1 last-conv: acc[px][80] (+= / init with bias) ----------------
__global__ __launch_bounds__(256, 2)
void k_acc_last(const f16* __restrict__ in, const f16* __restrict__ pack,
                const float* __restrict__ bias, float* __restrict__ accp, int bi)
{
    int lane = threadIdx.x & 63;
    int wid  = (blockIdx.x << 2) | (threadIdx.x >> 6);
    int row  = wid >> 2;
    int col0 = (wid & 3) << 6;
    int l15 = lane & 15, lk = lane >> 4;

    f32x4 acc[5][4];
#pragma unroll
    for (int i = 0; i < 5; ++i)
#pragma unroll
        for (int j = 0; j < 4; ++j)
            acc[i][j] = (f32x4){0.f, 0.f, 0.f, 0.f};

    const f16* bb = in + ((size_t)(row+1)*256 + col0 + l15)*CSTR + lk*8;
    const f16* ap = pack + (size_t)bi*PKL_BI + (size_t)lane*8;
    for (int cb = 0; cb < 7; ++cb) {
        f16x8 bh[4], bl[4];
#pragma unroll
        for (int pb = 0; pb < 4; ++pb) {
            const f16* p = bb + (size_t)pb*(16*CSTR) + cb*64;
            bh[pb] = *(const f16x8*)p;
            bl[pb] = *(const f16x8*)(p + 32);
        }
        const f16* a = ap + cb*PKL_CB;
#pragma unroll
        for (int ob = 0; ob < 5; ++ob) {
            f16x8 ah = *(const f16x8*)(a + ob*1024);
            f16x8 al = *(const f16x8*)(a + ob*1024 + 512);
#pragma unroll
            for (int pb = 0; pb < 4; ++pb) {
                acc[ob][pb] = MFMA16(ah, bh[pb], acc[ob][pb]);
                acc[ob][pb] = MFMA16(ah, bl[pb], acc[ob][pb]);
                acc[ob][pb] = MFMA16(al, bh[pb], acc[ob][pb]);
            }
        }
    }
#pragma unroll
    for (int ob = 0; ob < 5; ++ob) {
        int oc0 = ob*16 + lk*4;
#pragma unroll
        for (int pb = 0; pb < 4; ++pb) {
            int px = row*256 + col0 + pb*16 + l15;
            float* dst = accp + (size_t)px*80 + oc0;
            f32x4 d = acc[ob][pb];
            if (bi == 0) {
                f32x4 b4;
#pragma unroll
                for (int r = 0; r < 4; ++r) b4[r] = bias[min(oc0 + r, 67)];
                *(f32x4*)dst = d + b4;
            } else {
                *(f32x4*)dst = *(const f32x4*)dst + d;
            }
        }
    }
}

// ---------------- smn = 3x3 conv(acc[4:68]) + mask_b  (plain f32) ----------------
__global__ void k_smn(const float* __restrict__ accp, const float* __restrict__ mw,
                      const float* __restrict__ mb, float* __restrict__ smn)
{
    int px = blockIdx.x*256 + threadIdx.x;
    int row = px >> 8, col = px & 255;
    float s0 = mb[0], s1 = mb[1];
    for (int ky = 0; ky < 3; ++ky) {
        int r = row + ky - 1;
        if ((unsigned)r > 255u) continue;
        for (int kx = 0; kx < 3; ++kx) {
            int c = col + kx - 1;
            if ((unsigned)c > 255u) continue;
            const float* ab = accp + ((size_t)r*256 + c)*80 + 4;
            const float* w  = mw + ky*3 + kx;
#pragma unroll
            for (int ch = 0; ch < 64; ch += 4) {
                f32x4 v = *(const f32x4*)(ab + ch);
                s0 += v[0]*w[(ch+0)*9] + v[1]*w[(ch+1)*9] + v[2]*w[(ch+2)*9] + v[3]*w[(ch+3)*9];
                s1 += v[0]*w[(64+ch+0)*9] + v[1]*w[(64+ch+1)*9] + v[2]*w[(64+ch+2)*9] + v[3]*w[(64+ch+3)*9];
            }
        }
    }
    smn[px]        = s0;
    smn[NPIX + px] = s1;
}

// ---------------- bilinear 2x upsample of acc (68 ch) → d_out[0..68) ----------------
__global__ void k_upsample(const float* __restrict__ accp, float* __restrict__ outp)
{
    int o = blockIdx.x*256 + threadIdx.x;
    int oy = o >> 9, ox = o & 511;
    int my = oy >> 1, mx = ox >> 1;
    int r0, r1, c0, c1; float wy0, wy1, wx0, wx1;
    if (oy & 1) { r0 = my;            r1 = min(my+1, 255); wy0 = 0.75f; wy1 = 0.25f; }
    else        { r0 = max(my-1, 0);  r1 = my;             wy0 = 0.25f; wy1 = 0.75f; }
    if (ox & 1) { c0 = mx;            c1 = min(mx+1, 255); wx0 = 0.75f; wx1 = 0.25f; }
    else        { c0 = max(mx-1, 0);  c1 = mx;             wx0 = 0.25f; wx1 = 0.75f; }
    const float* p00 = accp + ((size_t)r0*256 + c0)*80;
    const float* p01 = accp + ((size_t)r0*256 + c1)*80;
    const float* p10 = accp + ((size_t)r1*256 + c0)*80;
    const float* p11 = accp + ((size_t)r1*256 + c1)*80;
    float w00 = wy0*wx0, w01 = wy0*wx1, w10 = wy1*wx0, w11 = wy1*wx1;
#pragma unroll
    for (int ch = 0; ch < 68; ch += 4) {
        f32x4 va = *(const f32x4*)(p00 + ch);
        f32x4 vb = *(const f32x4*)(p01 + ch);
        f32x4 vc = *(const f32x4*)(p10 + ch);
        f32x4 vd = *(const f32x4*)(p11 + ch);
        f32x4 v;
#pragma unroll
        for (int r = 0; r < 4; ++r)
            v[r] = w00*va[r] + w01*vb[r] + w10*vc[r] + w11*vd[r];
        outp[(size_t)(ch+0)*262144 + o] = v[0];
        outp[(size_t)(ch+1)*262144 + o] = v[1];
        outp[(size_t)(ch+2)*262144 + o] = v[2];
        outp[(size_t)(ch+3)*262144 + o] = v[3];
    }
}

// ---------------- mask_next = (up(smn0) > up(smn1)) * repeat2(space_mask) ----------------
__global__ void k_mask(const float* __restrict__ smn, const float* __restrict__ sm,
                       float* __restrict__ outp)
{
    int o = blockIdx.x*256 + threadIdx.x;
    int oy = o >> 9, ox = o & 511;
    int my = oy >> 1, mx = ox >> 1;
    int r0, r1, c0, c1; float wy0, wy1, wx0, wx1;
    if (oy & 1) { r0 = my;            r1 = min(my+1, 255); wy0 = 0.75f; wy1 = 0.25f; }
    else        { r0 = max(my-1, 0);  r1 = my;             wy0 = 0.25f; wy1 = 0.75f; }
    if (ox & 1) { c0 = mx;            c1 = min(mx+1, 255); wx0 = 0.75f; wx1 = 0.25f; }
    else        { c0 = max(mx-1, 0);  c1 = mx;             wx0 = 0.25f; wx1 = 0.75f; }
    float w00 = wy0*wx0, w01 = wy0*wx1, w10 = wy1*wx0, w11 = wy1*wx1;
    int i00 = r0*256 + c0, i01 = r0*256 + c1, i10 = r1*256 + c0, i11 = r1*256 + c1;
    float s0 = w00*smn[i00] + w01*smn[i01] + w10*smn[i10] + w11*smn[i11];
    float s1 = w00*smn[NPIX+i00] + w01*smn[NPIX+i01] + w10*smn[NPIX+i10] + w11*smn[NPIX+i11];
    outp[(size_t)68*262144 + o] = (s0 > s1) ? sm[my*256 + mx] : 0.f;
}

// ---------------- launcher ----------------
extern "C" void kernel_launch(void* const* d_in, const int* in_sizes, int n_in,
                              void* d_out, int out_size, void* d_ws, size_t ws_size,
                              hipStream_t stream)
{
    const float* feat0  = (const float*)d_in[0];
    const float* feat1  = (const float*)d_in[1];
    const float* featd  = (const float*)d_in[2];
    const float* flow   = (const float*)d_in[3];
    const float* smask  = (const float*)d_in[4];
    const float* head_w = (const float*)d_in[5];
    const float* head_a = (const float*)d_in[6];
    const float* conv_w = (const float*)d_in[7];
    const float* conv_a = (const float*)d_in[8];
    const float* last_w = (const float*)d_in[9];
    const float* last_b = (const float*)d_in[10];
    const float* mask_w = (const float*)d_in[11];
    const float* mask_b = (const float*)d_in[12];
    float* outp = (float*)d_out;

    char* ws = (char*)d_ws;
    size_t off = 4096;                        // front guard (col-1 underflow reads)
    f16* bufA = (f16*)(ws + off); off += SBUF + 4096;
    f16* bufB = (f16*)(ws + off); off += SBUF + 4096;
    f16* packc = (f16*)(ws + off); off += (size_t)4*PK_CONV*2;
    f16* packl = (f16*)(ws + off); off += (size_t)4*PKL_BI*2;
    float* accp = (float*)(ws + off); off += (size_t)NPIX*80*4;
    float* smn  = (float*)(ws + off); off += (size_t)2*NPIX*4;

    // zero the 2 pad rows of each buffer (rows 0 and 257)
    hipMemsetAsync(bufA, 0, RB, stream);
    hipMemsetAsync((char*)bufA + (size_t)257*RB, 0, RB, stream);
    hipMemsetAsync(bufB, 0, RB, stream);
    hipMemsetAsync((char*)bufB + (size_t)257*RB, 0, RB, stream);

    k_pack_conv<<<1764, 256, 0, stream>>>(head_w, conv_w, packc);
    k_pack_last<<<70, 256, 0, stream>>>(last_w, packl);
    k_warp_concat<<<256, 256, 0, stream>>>(feat0, feat1, featd, flow, bufA);

    // head: x0(bufA) -> bufB = outs[0]
    k_conv3x3<<<512, 256, 0, stream>>>(bufA, bufB, packc, head_a, smask);
    k_acc_last<<<256, 256, 0, stream>>>(bufB, packl, last_b, accp, 0);
    // layer1: bufB -> bufA = outs[1]
    k_conv3x3<<<512, 256, 0, stream>>>(bufB, bufA, packc + (size_t)1*PK_CONV, conv_a, smask);
    k_acc_last<<<256, 256, 0, stream>>>(bufA, packl, last_b, accp, 1);
    // layer2: bufA -> bufB = outs[2]
    k_conv3x3<<<512, 256, 0, stream>>>(bufA, bufB, packc + (size_t)2*PK_CONV, conv_a + 196, smask);
    k_acc_last<<<256, 256, 0, stream>>>(bufB, packl, last_b, accp, 2);
    // layer3: bufB -> bufA = outs[3]
    k_conv3x3<<<512, 256, 0, stream>>>(bufB, bufA, packc + (size_t)3*PK_CONV, conv_a + 392, smask);
    k_acc_last<<<256, 256, 0, stream>>>(bufA, packl, last_b, accp, 3);

    k_smn<<<256, 256, 0, stream>>>(accp, mask_w, mask_b, smn);
    k_upsample<<<1024, 256, 0, stream>>>(accp, outp);
    k_mask<<<1024, 256, 0, stream>>>(smn, smask, outp);
}

// Round 2
// 830.627 us; speedup vs baseline: 1.3924x; 1.3924x over previous
//
#include <hip/hip_runtime.h>

typedef _Float16 f16;
typedef _Float16 f16x8 __attribute__((ext_vector_type(8)));
typedef _Float16 f16x4 __attribute__((ext_vector_type(4)));
typedef float    f32x4 __attribute__((ext_vector_type(4)));

#define MFMA16(a,b,c) __builtin_amdgcn_mfma_f32_16x16x32_f16(a,b,c,0,0,0)

#define NPIX 65536
#define CSTR 448              // halves per pixel: 7 cb * (32 hi + 32 lo)
#define RB   (256*CSTR*2)     // bytes per buffer row = 229376
#define SBUF ((size_t)258*256*CSTR*2)   // 59,179,008 bytes (258 rows incl. 2 pad)

// weight pack strides (halves)
#define PK_OB   1024
#define PK_CB   14336   // 14*2*512
#define PK_TAP  100352  // 7*PK_CB
#define PK_CONV 903168  // 9*PK_TAP
#define PKL_CB  5120    // 5*2*512
#define PKL_BI  35840   // 7*PKL_CB

// LDS stage buffer: 130 px x 128 B  (64 halves/px, 8x16B slots, XOR-swizzled)
#define STG_BYTES 16640
#define STG_CHUNKS 1040   // 130 px * 8 slots

// ---------------- weight packing ----------------
__global__ void k_pack_conv(const float* __restrict__ head_w,
                            const float* __restrict__ conv_w,
                            f16* __restrict__ dst)
{
    int t = blockIdx.x*256 + threadIdx.x;
    if (t >= 4*9*7*14*2*64) return;
    int lane = t & 63; t >>= 6;
    int sel  = t & 1;  t >>= 1;
    int ob   = t % 14; t /= 14;
    int cb   = t % 7;  t /= 7;
    int tap  = t % 9;  t /= 9;
    int li   = t;
    const float* W = (li == 0) ? head_w : (conv_w + (size_t)(li-1)*196*196*9);
    int oc  = ob*16 + (lane & 15);
    int ic0 = cb*32 + (lane >> 4)*8;
    f16x8 v;
#pragma unroll
    for (int j = 0; j < 8; ++j) {
        int ic = ic0 + j;
        float x = 0.f;
        if (oc < 196 && ic < 196) x = W[((size_t)oc*196 + ic)*9 + tap];
        f16 h = (f16)x;
        v[j] = (sel == 0) ? h : (f16)(x - (float)h);
    }
    *(f16x8*)(dst + (size_t)li*PK_CONV +
              (((size_t)((tap*7+cb)*14 + ob)*2 + sel)*64 + lane)*8) = v;
}

__global__ void k_pack_last(const float* __restrict__ last_w, f16* __restrict__ dst)
{
    int t = blockIdx.x*256 + threadIdx.x;
    if (t >= 4*7*5*2*64) return;
    int lane = t & 63; t >>= 6;
    int sel  = t & 1;  t >>= 1;
    int ob   = t % 5;  t /= 5;
    int cb   = t % 7;  t /= 7;
    int bi   = t;
    int oc = ob*16 + (lane & 15);
    int k0 = cb*32 + (lane >> 4)*8;
    f16x8 v;
#pragma unroll
    for (int j = 0; j < 8; ++j) {
        int k = k0 + j;
        float x = 0.f;
        if (oc < 68 && k < 196) x = last_w[(size_t)oc*784 + bi*196 + k];
        f16 h = (f16)x;
        v[j] = (sel == 0) ? h : (f16)(x - (float)h);
    }
    *(f16x8*)(dst + (((size_t)((bi*7+cb)*5 + ob)*2 + sel)*64 + lane)*8) = v;
}

// ---------------- warp + concat → x0 ----------------
struct Gath { int o00,o01,o10,o11; float w00,w01,w10,w11; };

__device__ inline Gath mk_gath(float pxf, float pyf)
{
    float x0 = floorf(pxf), y0 = floorf(pyf);
    float x1 = x0 + 1.f, y1 = y0 + 1.f;
    float wx1 = pxf - x0, wx0 = 1.f - wx1;
    float wy1 = pyf - y0, wy0 = 1.f - wy1;
    bool vx0 = (x0 >= 0.f) && (x0 <= 255.f);
    bool vx1 = (x1 >= 0.f) && (x1 <= 255.f);
    bool vy0 = (y0 >= 0.f) && (y0 <= 255.f);
    bool vy1 = (y1 >= 0.f) && (y1 <= 255.f);
    int ix0 = min(max((int)x0, 0), 255);
    int ix1 = min(max((int)x1, 0), 255);
    int iy0 = min(max((int)y0, 0), 255);
    int iy1 = min(max((int)y1, 0), 255);
    Gath g;
    g.o00 = iy0*256 + ix0; g.w00 = (vx0 && vy0) ? wx0*wy0 : 0.f;
    g.o01 = iy0*256 + ix1; g.w01 = (vx1 && vy0) ? wx1*wy0 : 0.f;
    g.o10 = iy1*256 + ix0; g.w10 = (vx0 && vy1) ? wx0*wy1 : 0.f;
    g.o11 = iy1*256 + ix1; g.w11 = (vx1 && vy1) ? wx1*wy1 : 0.f;
    return g;
}

__device__ inline void store4(f16* __restrict__ op, int c0,
                              float a, float b, float c, float d)
{
    f16x4 hi, lo;
    f16 h;
    h = (f16)a; hi[0] = h; lo[0] = (f16)(a - (float)h);
    h = (f16)b; hi[1] = h; lo[1] = (f16)(b - (float)h);
    h = (f16)c; hi[2] = h; lo[2] = (f16)(c - (float)h);
    h = (f16)d; hi[3] = h; lo[3] = (f16)(d - (float)h);
    f16* p = op + (c0 >> 5)*64 + (c0 & 31);
    *(f16x4*)p        = hi;
    *(f16x4*)(p + 32) = lo;
}

__global__ void k_warp_concat(const float* __restrict__ f0, const float* __restrict__ f1,
                              const float* __restrict__ fd, const float* __restrict__ flow,
                              f16* __restrict__ out)
{
    int px = blockIdx.x*256 + threadIdx.x;
    int row = px >> 8, col = px & 255;
    f16* op = out + ((size_t)(row+1)*256 + col)*CSTR;
    Gath g0 = mk_gath((float)col + flow[px],          (float)row + flow[NPIX   + px]);
    Gath g1 = mk_gath((float)col + flow[2*NPIX + px], (float)row + flow[3*NPIX + px]);
#pragma unroll
    for (int c = 0; c < 64; c += 4) {
        float v[4];
#pragma unroll
        for (int r = 0; r < 4; ++r) {
            const float* im = f0 + (size_t)(c+r)*NPIX;
            v[r] = g0.w00*im[g0.o00] + g0.w01*im[g0.o01] + g0.w10*im[g0.o10] + g0.w11*im[g0.o11];
        }
        store4(op, c, v[0], v[1], v[2], v[3]);
    }
#pragma unroll
    for (int c = 0; c < 64; c += 4) {
        float v[4];
#pragma unroll
        for (int r = 0; r < 4; ++r) {
            const float* im = f1 + (size_t)(c+r)*NPIX;
            v[r] = g1.w00*im[g1.o00] + g1.w01*im[g1.o01] + g1.w10*im[g1.o10] + g1.w11*im[g1.o11];
        }
        store4(op, 64 + c, v[0], v[1], v[2], v[3]);
    }
#pragma unroll
    for (int c = 0; c < 64; c += 4) {
        store4(op, 128 + c, fd[(size_t)(c+0)*NPIX + px], fd[(size_t)(c+1)*NPIX + px],
                            fd[(size_t)(c+2)*NPIX + px], fd[(size_t)(c+3)*NPIX + px]);
    }
    store4(op, 192, flow[px], flow[NPIX+px], flow[2*NPIX+px], flow[3*NPIX+px]);
#pragma unroll
    for (int c = 196; c < 224; c += 4) store4(op, c, 0.f, 0.f, 0.f, 0.f);
}

// ---------------- 3x3 conv (196->196, split-f16, LDS-staged, fused prelu*mask) ----
// block = 448 threads (7 waves), tile = 128 px x 224 oc
// wave w handles ob {2w, 2w+1} x 8 px-subtiles of 16
// LDS: per (ky,cb) slice of 130 px x 64 halves, XOR-swizzled, double-buffered
__global__ __launch_bounds__(448, 4)
void k_conv3x3(const f16* __restrict__ in, f16* __restrict__ out,
               const f16* __restrict__ pack, const float* __restrict__ alpha,
               const float* __restrict__ mask)
{
    __shared__ __align__(16) char bs[2*STG_BYTES];

    // bijective XCD swizzle: 512 blocks, 64 per XCD chunk
    int bid = blockIdx.x;
    int wg  = (bid & 7)*64 + (bid >> 3);
    int row  = wg >> 1;
    int col0 = (wg & 1) << 7;

    int tid  = threadIdx.x;
    int lane = tid & 63;
    int w    = tid >> 6;
    int l15  = lane & 15, lk = lane >> 4;

    f32x4 acc[2][8];
#pragma unroll
    for (int o = 0; o < 2; ++o)
#pragma unroll
        for (int pb = 0; pb < 8; ++pb)
            acc[o][pb] = (f32x4){0.f,0.f,0.f,0.f};

    const f16x8 Z8 = {(f16)0,(f16)0,(f16)0,(f16)0,(f16)0,(f16)0,(f16)0,(f16)0};

    // ---- staging helpers (inline) ----
    // chunk c: px p = c>>3 (0..129), slot sl = c&7; global col cp = col0-1+p
    f16x8 sr[3];
    int ccap[3];
#pragma unroll
    for (int u = 0; u < 3; ++u) ccap[u] = tid + u*448;

    // prologue: stage slice 0 (ky=0, cb=0)
    {
#pragma unroll
        for (int u = 0; u < 3; ++u) {
            int c = ccap[u];
            f16x8 v = Z8;
            if (c < STG_CHUNKS) {
                int p = c >> 3, sl = c & 7;
                int cp = col0 - 1 + p;
                if ((unsigned)cp < 256u)
                    v = *(const f16x8*)(in + ((size_t)row*256 + cp)*CSTR + sl*8);
            }
            sr[u] = v;
        }
#pragma unroll
        for (int u = 0; u < 3; ++u) {
            int c = ccap[u];
            if (c < STG_CHUNKS) {
                int p = c >> 3, sl = c & 7;
                *(f16x8*)(bs + p*128 + ((sl ^ (p & 7)) << 4)) = sr[u];
            }
        }
    }
    __syncthreads();

    for (int idx = 0; idx < 21; ++idx) {
        int ky = idx / 7;
        int cb = idx - ky*7;

        // issue next slice's global loads early (latency hides under compute)
        int nidx = idx + 1;
        if (nidx < 21) {
            int nky = nidx / 7;
            int ncb = nidx - nky*7;
#pragma unroll
            for (int u = 0; u < 3; ++u) {
                int c = ccap[u];
                f16x8 v = Z8;
                if (c < STG_CHUNKS) {
                    int p = c >> 3, sl = c & 7;
                    int cp = col0 - 1 + p;
                    if ((unsigned)cp < 256u)
                        v = *(const f16x8*)(in + ((size_t)(row+nky)*256 + cp)*CSTR + ncb*64 + sl*8);
                }
                sr[u] = v;
            }
        }

        // compute from buf[idx&1]
        const char* bufc = bs + (idx & 1)*STG_BYTES;
#pragma unroll
        for (int kx = 0; kx < 3; ++kx) {
            const f16* ap = pack + ((size_t)(((ky*3+kx)*7 + cb)*14 + 2*w)*2)*512 + (size_t)lane*8;
            f16x8 ah0 = *(const f16x8*)(ap);
            f16x8 al0 = *(const f16x8*)(ap + 512);
            f16x8 ah1 = *(const f16x8*)(ap + 1024);
            f16x8 al1 = *(const f16x8*)(ap + 1536);
            int t = l15 + kx;
            int sz = t & 7;
            int hoff = t*128 + ((lk ^ sz) << 4);
            int loff = t*128 + (((4+lk) ^ sz) << 4);
#pragma unroll
            for (int pb = 0; pb < 8; ++pb) {
                f16x8 bh = *(const f16x8*)(bufc + hoff + pb*2048);
                f16x8 bl = *(const f16x8*)(bufc + loff + pb*2048);
                acc[0][pb] = MFMA16(ah0, bh, acc[0][pb]);
                acc[0][pb] = MFMA16(ah0, bl, acc[0][pb]);
                acc[0][pb] = MFMA16(al0, bh, acc[0][pb]);
                acc[1][pb] = MFMA16(ah1, bh, acc[1][pb]);
                acc[1][pb] = MFMA16(ah1, bl, acc[1][pb]);
                acc[1][pb] = MFMA16(al1, bh, acc[1][pb]);
            }
        }

        // write next slice into the other buffer
        if (nidx < 21) {
            char* bufn = bs + (nidx & 1)*STG_BYTES;
#pragma unroll
            for (int u = 0; u < 3; ++u) {
                int c = ccap[u];
                if (c < STG_CHUNKS) {
                    int p = c >> 3, sl = c & 7;
                    *(f16x8*)(bufn + p*128 + ((sl ^ (p & 7)) << 4)) = sr[u];
                }
            }
        }
        __syncthreads();
    }

    // epilogue: prelu * mask, split-f16 store
    float mv[8];
#pragma unroll
    for (int pb = 0; pb < 8; ++pb) mv[pb] = mask[row*256 + col0 + pb*16 + l15];
#pragma unroll
    for (int o = 0; o < 2; ++o) {
        int oc0 = (2*w + o)*16 + lk*4;
        f32x4 a4 = *(const f32x4*)(alpha + min(oc0, 192));
#pragma unroll
        for (int pb = 0; pb < 8; ++pb) {
            f32x4 d = acc[o][pb];
            f16x4 hi, lo;
#pragma unroll
            for (int r = 0; r < 4; ++r) {
                float v = d[r];
                v = (v >= 0.f ? v : a4[r]*v) * mv[pb];
                f16 h = (f16)v;
                hi[r] = h;
                lo[r] = (f16)(v - (float)h);
            }
            f16* op = out + ((size_t)(row+1)*256 + col0 + pb*16 + l15)*CSTR + (oc0 >> 5)*64 + (oc0 & 31);
            *(f16x4*)op        = hi;
            *(f16x4*)(op + 32) = lo;
        }
    }
}

// ---------------- incremental 1x1 last-conv: acc[px][80] (+= / init with bias) ----------------
__global__ __launch_bounds__(256, 4)
void k_acc_last(const f16* __restrict__ in, const f16* __restrict__ pack,
                const float* __restrict__ bias, float* __restrict__ accp, int bi)
{
    int lane = threadIdx.x & 63;
    int wid  = (blockIdx.x << 2) | (threadIdx.x >> 6);
    int row  = wid >> 3;
    int col0 = (wid & 7) << 5;
    int l15 = lane & 15, lk = lane >> 4;

    f32x4 acc[5][2];
#pragma unroll
    for (int i = 0; i < 5; ++i)
#pragma unroll
        for (int j = 0; j < 2; ++j)
            acc[i][j] = (f32x4){0.f, 0.f, 0.f, 0.f};

    const f16* bb = in + ((size_t)(row+1)*256 + col0 + l15)*CSTR + lk*8;
    const f16* ap = pack + (size_t)bi*PKL_BI + (size_t)lane*8;
    for (int cb = 0; cb < 7; ++cb) {
        f16x8 bh[2], bl[2];
#pragma unroll
        for (int pb = 0; pb < 2; ++pb) {
            const f16* p = bb + (size_t)pb*(16*CSTR) + cb*64;
            bh[pb] = *(const f16x8*)p;
            bl[pb] = *(const f16x8*)(p + 32);
        }
        const f16* a = ap + cb*PKL_CB;
#pragma unroll
        for (int ob = 0; ob < 5; ++ob) {
            f16x8 ah = *(const f16x8*)(a + ob*1024);
            f16x8 al = *(const f16x8*)(a + ob*1024 + 512);
#pragma unroll
            for (int pb = 0; pb < 2; ++pb) {
                acc[ob][pb] = MFMA16(ah, bh[pb], acc[ob][pb]);
                acc[ob][pb] = MFMA16(ah, bl[pb], acc[ob][pb]);
                acc[ob][pb] = MFMA16(al, bh[pb], acc[ob][pb]);
            }
        }
    }
#pragma unroll
    for (int ob = 0; ob < 5; ++ob) {
        int oc0 = ob*16 + lk*4;
#pragma unroll
        for (int pb = 0; pb < 2; ++pb) {
            int px = row*256 + col0 + pb*16 + l15;
            float* dst = accp + (size_t)px*80 + oc0;
            f32x4 d = acc[ob][pb];
            if (bi == 0) {
                f32x4 b4;
#pragma unroll
                for (int r = 0; r < 4; ++r) b4[r] = bias[min(oc0 + r, 67)];
                *(f32x4*)dst = d + b4;
            } else {
                *(f32x4*)dst = *(const f32x4*)dst + d;
            }
        }
    }
}

// ---------------- smn = 3x3 conv(acc[4:68]) + mask_b  (plain f32) ----------------
__global__ void k_smn(const float* __restrict__ accp, const float* __restrict__ mw,
                      const float* __restrict__ mb, float* __restrict__ smn)
{
    int px = blockIdx.x*256 + threadIdx.x;
    int row = px >> 8, col = px & 255;
    float s0 = mb[0], s1 = mb[1];
    for (int ky = 0; ky < 3; ++ky) {
        int r = row + ky - 1;
        if ((unsigned)r > 255u) continue;
        for (int kx = 0; kx < 3; ++kx) {
            int c = col + kx - 1;
            if ((unsigned)c > 255u) continue;
            const float* ab = accp + ((size_t)r*256 + c)*80 + 4;
            const float* w  = mw + ky*3 + kx;
#pragma unroll
            for (int ch = 0; ch < 64; ch += 4) {
                f32x4 v = *(const f32x4*)(ab + ch);
                s0 += v[0]*w[(ch+0)*9] + v[1]*w[(ch+1)*9] + v[2]*w[(ch+2)*9] + v[3]*w[(ch+3)*9];
                s1 += v[0]*w[(64+ch+0)*9] + v[1]*w[(64+ch+1)*9] + v[2]*w[(64+ch+2)*9] + v[3]*w[(64+ch+3)*9];
            }
        }
    }
    smn[px]        = s0;
    smn[NPIX + px] = s1;
}

// ---------------- bilinear 2x upsample of acc (68 ch) → d_out[0..68) ----------------
__global__ void k_upsample(const float* __restrict__ accp, float* __restrict__ outp)
{
    int o = blockIdx.x*256 + threadIdx.x;
    int oy = o >> 9, ox = o & 511;
    int my = oy >> 1, mx = ox >> 1;
    int r0, r1, c0, c1; float wy0, wy1, wx0, wx1;
    if (oy & 1) { r0 = my;            r1 = min(my+1, 255); wy0 = 0.75f; wy1 = 0.25f; }
    else        { r0 = max(my-1, 0);  r1 = my;             wy0 = 0.25f; wy1 = 0.75f; }
    if (ox & 1) { c0 = mx;            c1 = min(mx+1, 255); wx0 = 0.75f; wx1 = 0.25f; }
    else        { c0 = max(mx-1, 0);  c1 = mx;             wx0 = 0.25f; wx1 = 0.75f; }
    const float* p00 = accp + ((size_t)r0*256 + c0)*80;
    const float* p01 = accp + ((size_t)r0*256 + c1)*80;
    const float* p10 = accp + ((size_t)r1*256 + c0)*80;
    const float* p11 = accp + ((size_t)r1*256 + c1)*80;
    float w00 = wy0*wx0, w01 = wy0*wx1, w10 = wy1*wx0, w11 = wy1*wx1;
#pragma unroll
    for (int ch = 0; ch < 68; ch += 4) {
        f32x4 va = *(const f32x4*)(p00 + ch);
        f32x4 vb = *(const f32x4*)(p01 + ch);
        f32x4 vc = *(const f32x4*)(p10 + ch);
        f32x4 vd = *(const f32x4*)(p11 + ch);
        f32x4 v;
#pragma unroll
        for (int r = 0; r < 4; ++r)
            v[r] = w00*va[r] + w01*vb[r] + w10*vc[r] + w11*vd[r];
        outp[(size_t)(ch+0)*262144 + o] = v[0];
        outp[(size_t)(ch+1)*262144 + o] = v[1];
        outp[(size_t)(ch+2)*262144 + o] = v[2];
        outp[(size_t)(ch+3)*262144 + o] = v[3];
    }
}

// ---------------- mask_next = (up(smn0) > up(smn1)) * repeat2(space_mask) ----------------
__global__ void k_mask(const float* __restrict__ smn, const float* __restrict__ sm,
                       float* __restrict__ outp)
{
    int o = blockIdx.x*256 + threadIdx.x;
    int oy = o >> 9, ox = o & 511;
    int my = oy >> 1, mx = ox >> 1;
    int r0, r1, c0, c1; float wy0, wy1, wx0, wx1;
    if (oy & 1) { r0 = my;            r1 = min(my+1, 255); wy0 = 0.75f; wy1 = 0.25f; }
    else        { r0 = max(my-1, 0);  r1 = my;             wy0 = 0.25f; wy1 = 0.75f; }
    if (ox & 1) { c0 = mx;            c1 = min(mx+1, 255); wx0 = 0.75f; wx1 = 0.25f; }
    else        { c0 = max(mx-1, 0);  c1 = mx;             wx0 = 0.25f; wx1 = 0.75f; }
    float w00 = wy0*wx0, w01 = wy0*wx1, w10 = wy1*wx0, w11 = wy1*wx1;
    int i00 = r0*256 + c0, i01 = r0*256 + c1, i10 = r1*256 + c0, i11 = r1*256 + c1;
    float s0 = w00*smn[i00] + w01*smn[i01] + w10*smn[i10] + w11*smn[i11];
    float s1 = w00*smn[NPIX+i00] + w01*smn[NPIX+i01] + w10*smn[NPIX+i10] + w11*smn[NPIX+i11];
    outp[(size_t)68*262144 + o] = (s0 > s1) ? sm[my*256 + mx] : 0.f;
}

// ---------------- launcher ----------------
extern "C" void kernel_launch(void* const* d_in, const int* in_sizes, int n_in,
                              void* d_out, int out_size, void* d_ws, size_t ws_size,
                              hipStream_t stream)
{
    const float* feat0  = (const float*)d_in[0];
    const float* feat1  = (const float*)d_in[1];
    const float* featd  = (const float*)d_in[2];
    const float* flow   = (const float*)d_in[3];
    const float* smask  = (const float*)d_in[4];
    const float* head_w = (const float*)d_in[5];
    const float* head_a = (const float*)d_in[6];
    const float* conv_w = (const float*)d_in[7];
    const float* conv_a = (const float*)d_in[8];
    const float* last_w = (const float*)d_in[9];
    const float* last_b = (const float*)d_in[10];
    const float* mask_w = (const float*)d_in[11];
    const float* mask_b = (const float*)d_in[12];
    float* outp = (float*)d_out;

    char* ws = (char*)d_ws;
    size_t off = 4096;
    f16* bufA = (f16*)(ws + off); off += SBUF + 4096;
    f16* bufB = (f16*)(ws + off); off += SBUF + 4096;
    f16* packc = (f16*)(ws + off); off += (size_t)4*PK_CONV*2;
    f16* packl = (f16*)(ws + off); off += (size_t)4*PKL_BI*2;
    float* accp = (float*)(ws + off); off += (size_t)NPIX*80*4;
    float* smn  = (float*)(ws + off); off += (size_t)2*NPIX*4;

    // zero the 2 pad rows of each buffer (rows 0 and 257)
    hipMemsetAsync(bufA, 0, RB, stream);
    hipMemsetAsync((char*)bufA + (size_t)257*RB, 0, RB, stream);
    hipMemsetAsync(bufB, 0, RB, stream);
    hipMemsetAsync((char*)bufB + (size_t)257*RB, 0, RB, stream);

    k_pack_conv<<<1764, 256, 0, stream>>>(head_w, conv_w, packc);
    k_pack_last<<<70, 256, 0, stream>>>(last_w, packl);
    k_warp_concat<<<256, 256, 0, stream>>>(feat0, feat1, featd, flow, bufA);

    // head: x0(bufA) -> bufB = outs[0]
    k_conv3x3<<<512, 448, 0, stream>>>(bufA, bufB, packc, head_a, smask);
    k_acc_last<<<512, 256, 0, stream>>>(bufB, packl, last_b, accp, 0);
    // layer1: bufB -> bufA = outs[1]
    k_conv3x3<<<512, 448, 0, stream>>>(bufB, bufA, packc + (size_t)1*PK_CONV, conv_a, smask);
    k_acc_last<<<512, 256, 0, stream>>>(bufA, packl, last_b, accp, 1);
    // layer2: bufA -> bufB = outs[2]
    k_conv3x3<<<512, 448, 0, stream>>>(bufA, bufB, packc + (size_t)2*PK_CONV, conv_a + 196, smask);
    k_acc_last<<<512, 256, 0, stream>>>(bufB, packl, last_b, accp, 2);
    // layer3: bufB -> bufA = outs[3]
    k_conv3x3<<<512, 448, 0, stream>>>(bufB, bufA, packc + (size_t)3*PK_CONV, conv_a + 392, smask);
    k_acc_last<<<512, 256, 0, stream>>>(bufA, packl, last_b, accp, 3);

    k_smn<<<256, 256, 0, stream>>>(accp, mask_w, mask_b, smn);
    k_upsample<<<1024, 256, 0, stream>>>(accp, outp);
    k_mask<<<1024, 256, 0, stream>>>(smn, smask, outp);
}